// Round 3
// baseline (187.152 us; speedup 1.0000x reference)
//
#include <hip/hip_runtime.h>
#include <math.h>

#define NUM_Q_ 10000
#define NUM_A_ 10000
#define DIM 128
#define MSZ 50
#define BB 64
#define NN 200
#define RPOS 8
#define SEG 8
#define SLEN 25   // NN/SEG

typedef float f4 __attribute__((ext_vector_type(4)));

// ---------------- Phase A: gather + w(softmax) + e(sigmoid) + ad(tanh) ----------------
__global__ __launch_bounds__(128) void phaseA(
    const int* __restrict__ q, const int* __restrict__ r, const int* __restrict__ a,
    const float* __restrict__ Kemb, const float* __restrict__ Vemb, const float* __restrict__ VAemb,
    const float* __restrict__ Mk, const float* __restrict__ eW, const float* __restrict__ eb,
    const float* __restrict__ aW, const float* __restrict__ ab,
    float* __restrict__ w_ws, float* __restrict__ e_ws, float* __restrict__ ad_ws)
{
    const int tid = threadIdx.x;
    const int pos0 = blockIdx.x * RPOS;
    __shared__ float s_s[RPOS][DIM];
    __shared__ float s_k[RPOS][DIM];

    #pragma unroll
    for (int p = 0; p < RPOS; ++p) {
        int pos = pos0 + p;
        int qi = q[pos], ri = r[pos], ai = a[pos];
        int xi = qi + NUM_Q_ * ri;
        int axi = ai + NUM_A_ * ri;
        s_k[p][tid] = Kemb[(size_t)qi * DIM + tid];
        s_s[p][tid] = Vemb[(size_t)xi * DIM + tid] + VAemb[(size_t)axi * DIM + tid];
    }
    __syncthreads();

    float acc_e[RPOS], acc_a[RPOS], acc_l[RPOS];
    #pragma unroll
    for (int p = 0; p < RPOS; ++p) { acc_e[p] = 0.f; acc_a[p] = 0.f; acc_l[p] = 0.f; }

    const bool hasM = (tid < MSZ);
    const f4* eWr = (const f4*)(eW + (size_t)tid * DIM);
    const f4* aWr = (const f4*)(aW + (size_t)tid * DIM);
    const f4* mkr = (const f4*)(Mk + (size_t)(hasM ? tid : 0) * DIM);

    for (int i4 = 0; i4 < DIM / 4; ++i4) {
        f4 we = eWr[i4];
        f4 wa = aWr[i4];
        #pragma unroll
        for (int c = 0; c < 4; ++c) {
            int i = i4 * 4 + c;
            #pragma unroll
            for (int p = 0; p < RPOS; ++p) {
                float sv = s_s[p][i];
                acc_e[p] = fmaf(sv, we[c], acc_e[p]);
                acc_a[p] = fmaf(sv, wa[c], acc_a[p]);
            }
        }
        if (hasM) {
            f4 mk = mkr[i4];
            #pragma unroll
            for (int c = 0; c < 4; ++c) {
                int i = i4 * 4 + c;
                #pragma unroll
                for (int p = 0; p < RPOS; ++p)
                    acc_l[p] = fmaf(s_k[p][i], mk[c], acc_l[p]);
            }
        }
    }

    float ebv = eb[tid], abv = ab[tid];
    #pragma unroll
    for (int p = 0; p < RPOS; ++p) {
        float ev = 1.f / (1.f + __expf(-(acc_e[p] + ebv)));
        float av = tanhf(acc_a[p] + abv);
        e_ws[(size_t)(pos0 + p) * DIM + tid] = ev;
        ad_ws[(size_t)(pos0 + p) * DIM + tid] = av;
    }

    if (tid < 64) {
        #pragma unroll
        for (int p = 0; p < RPOS; ++p) {
            float lv = hasM ? acc_l[p] : -1e30f;
            float mx = lv;
            #pragma unroll
            for (int off = 32; off >= 1; off >>= 1)
                mx = fmaxf(mx, __shfl_xor(mx, off, 64));
            float ex = hasM ? __expf(lv - mx) : 0.f;
            float sm = ex;
            #pragma unroll
            for (int off = 32; off >= 1; off >>= 1)
                sm += __shfl_xor(sm, off, 64);
            if (hasM) w_ws[(size_t)(pos0 + p) * MSZ + tid] = ex / sm;
        }
    }
}

// ---------------- scanP1: per-segment affine aggregates (A,B) per (m,d) ----------------
// bid = ((b*2 + dc)*8 + seg); 64 threads = 1 wave; lane = d within half.
__global__ __launch_bounds__(64) void scanP1(
    const float* __restrict__ w_ws, const float* __restrict__ e_ws, const float* __restrict__ ad_ws,
    float* __restrict__ Aseg, float* __restrict__ Bseg)
{
    const int bid = blockIdx.x;
    const int seg = bid & 7;
    const int dc  = (bid >> 3) & 1;
    const int b   = bid >> 4;
    const int lane = threadIdx.x;
    const int t0 = seg * SLEN;

    __shared__ float w_s[SLEN * 52];
    __shared__ float e_s[SLEN * 64];
    __shared__ float a_s[SLEN * 64];

    const float* wb = w_ws + ((size_t)b * NN + t0) * MSZ;
    const float* eb2 = e_ws + ((size_t)b * NN + t0) * DIM + dc * 64;
    const float* ab2 = ad_ws + ((size_t)b * NN + t0) * DIM + dc * 64;
    for (int k = lane; k < SLEN * MSZ; k += 64) {
        int row = k / MSZ, col = k - row * MSZ;
        w_s[row * 52 + col] = wb[k];
    }
    for (int k = lane; k < SLEN * 64; k += 64) {
        int row = k >> 6, col = k & 63;
        e_s[k] = eb2[row * DIM + col];
        a_s[k] = ab2[row * DIM + col];
    }
    __syncthreads();

    float A[MSZ], Bv[MSZ];
    #pragma unroll
    for (int j = 0; j < MSZ; ++j) { A[j] = 1.f; Bv[j] = 0.f; }

    for (int tc = 0; tc < SLEN; ++tc) {
        float ev = e_s[tc * 64 + lane];
        float av = a_s[tc * 64 + lane];
        const float* wr = &w_s[tc * 52];
        #pragma unroll
        for (int j = 0; j < MSZ; ++j) {
            float wj = wr[j];
            float f = fmaf(-wj, ev, 1.f);
            Bv[j] = fmaf(Bv[j], f, wj * av);
            A[j] *= f;
        }
    }

    float* Ao = Aseg + ((size_t)b * SEG + seg) * MSZ * DIM + dc * 64 + lane;
    float* Bo = Bseg + ((size_t)b * SEG + seg) * MSZ * DIM + dc * 64 + lane;
    #pragma unroll
    for (int j = 0; j < MSZ; ++j) { Ao[j * DIM] = A[j]; Bo[j * DIM] = Bv[j]; }
}

// ---------------- scanC: combine segments sequentially; emit Mstart + Mv[b,0] ----------------
__global__ __launch_bounds__(256) void scanC(
    const float* __restrict__ Mv0, const float* __restrict__ Aseg, const float* __restrict__ Bseg,
    float* __restrict__ Mstart, float* __restrict__ Mv)
{
    const int idx = blockIdx.x * 256 + threadIdx.x;   // < 64*6400
    const int b = idx / (MSZ * DIM);
    const int r = idx - b * (MSZ * DIM);
    float M = Mv0[r];
    Mv[(size_t)b * (NN + 1) * MSZ * DIM + r] = M;
    #pragma unroll
    for (int s = 0; s < SEG; ++s) {
        size_t o = ((size_t)b * SEG + s) * MSZ * DIM + r;
        Mstart[o] = M;
        M = fmaf(Aseg[o], M, Bseg[o]);
    }
}

// ---------------- scanP2: replay segment, stream Mv + full reads ----------------
__global__ __launch_bounds__(64) void scanP2(
    const float* __restrict__ Mstart,
    const float* __restrict__ w_ws, const float* __restrict__ e_ws, const float* __restrict__ ad_ws,
    float* __restrict__ rp, float* __restrict__ Mv)
{
    const int bid = blockIdx.x;
    const int seg = bid & 7;
    const int dc  = (bid >> 3) & 1;
    const int b   = bid >> 4;
    const int lane = threadIdx.x;
    const int t0 = seg * SLEN;

    __shared__ float w_s[SLEN * 52];
    __shared__ float e_s[SLEN * 64];
    __shared__ float a_s[SLEN * 64];

    const float* wb = w_ws + ((size_t)b * NN + t0) * MSZ;
    const float* eb2 = e_ws + ((size_t)b * NN + t0) * DIM + dc * 64;
    const float* ab2 = ad_ws + ((size_t)b * NN + t0) * DIM + dc * 64;
    for (int k = lane; k < SLEN * MSZ; k += 64) {
        int row = k / MSZ, col = k - row * MSZ;
        w_s[row * 52 + col] = wb[k];
    }
    for (int k = lane; k < SLEN * 64; k += 64) {
        int row = k >> 6, col = k & 63;
        e_s[k] = eb2[row * DIM + col];
        a_s[k] = ab2[row * DIM + col];
    }
    __syncthreads();

    float M[MSZ];
    const float* Ms = Mstart + ((size_t)b * SEG + seg) * MSZ * DIM + dc * 64 + lane;
    #pragma unroll
    for (int j = 0; j < MSZ; ++j) M[j] = Ms[j * DIM];

    float* out = Mv + (size_t)b * (NN + 1) * MSZ * DIM + (size_t)(t0 + 1) * MSZ * DIM
               + dc * 64 + lane;
    float* rpo = rp + ((size_t)b * NN + t0) * DIM + dc * 64 + lane;

    for (int tc = 0; tc < SLEN; ++tc) {
        float ev = e_s[tc * 64 + lane];
        float av = a_s[tc * 64 + lane];
        const float* wr = &w_s[tc * 52];
        float pr = 0.f;
        #pragma unroll
        for (int j = 0; j < MSZ; ++j) {
            float wj = wr[j];
            pr = fmaf(wj, M[j], pr);               // read pre-update memory
            float t1 = fmaf(-M[j], ev, av);        // a - M*e
            M[j] = fmaf(wj, t1, M[j]);             // M + w*(a - M*e)
        }
        rpo[(size_t)tc * DIM] = pr;
        #pragma unroll
        for (int j = 0; j < MSZ; ++j) out[j * DIM] = M[j];
        out += MSZ * DIM;
    }
}

// ---------------- Phase C: f = tanh([reads,k]@fW^T+fb), p = sigmoid(f@pW+pb) ----------------
__global__ __launch_bounds__(128) void phaseC(
    const int* __restrict__ q, const float* __restrict__ Kemb,
    const float* __restrict__ rp,
    const float* __restrict__ fW, const float* __restrict__ fb,
    const float* __restrict__ pW, const float* __restrict__ pb,
    float* __restrict__ p_out)
{
    const int tid = threadIdx.x;
    const int pos0 = blockIdx.x * RPOS;
    __shared__ float s_cat[RPOS][2 * DIM];
    __shared__ float part[2][RPOS];

    #pragma unroll
    for (int p = 0; p < RPOS; ++p) {
        int pos = pos0 + p;
        s_cat[p][tid] = rp[(size_t)pos * DIM + tid];
        s_cat[p][DIM + tid] = Kemb[(size_t)q[pos] * DIM + tid];
    }
    __syncthreads();

    float acc[RPOS];
    #pragma unroll
    for (int p = 0; p < RPOS; ++p) acc[p] = 0.f;

    const f4* fWr = (const f4*)(fW + (size_t)tid * 2 * DIM);
    for (int i4 = 0; i4 < (2 * DIM) / 4; ++i4) {
        f4 wf = fWr[i4];
        #pragma unroll
        for (int c = 0; c < 4; ++c) {
            int i = i4 * 4 + c;
            #pragma unroll
            for (int p = 0; p < RPOS; ++p)
                acc[p] = fmaf(s_cat[p][i], wf[c], acc[p]);
        }
    }

    float fbv = fb[tid], pwv = pW[tid];
    const int wv = tid >> 6, ln = tid & 63;
    #pragma unroll
    for (int p = 0; p < RPOS; ++p) {
        float v = tanhf(acc[p] + fbv) * pwv;
        #pragma unroll
        for (int off = 32; off >= 1; off >>= 1)
            v += __shfl_xor(v, off, 64);
        if (ln == 0) part[wv][p] = v;
    }
    __syncthreads();
    if (tid < RPOS) {
        float pv = part[0][tid] + part[1][tid] + pb[0];
        p_out[pos0 + tid] = 1.f / (1.f + __expf(-pv));
    }
}

extern "C" void kernel_launch(void* const* d_in, const int* in_sizes, int n_in,
                              void* d_out, int out_size, void* d_ws, size_t ws_size,
                              hipStream_t stream) {
    const int*   q     = (const int*)d_in[0];
    const int*   r     = (const int*)d_in[1];
    const int*   a     = (const int*)d_in[2];
    const float* Kemb  = (const float*)d_in[3];
    const float* Vemb  = (const float*)d_in[4];
    const float* VAemb = (const float*)d_in[5];
    const float* Mk    = (const float*)d_in[6];
    const float* Mv0   = (const float*)d_in[7];
    const float* fW    = (const float*)d_in[8];
    const float* fb    = (const float*)d_in[9];
    const float* pW    = (const float*)d_in[10];
    const float* pb    = (const float*)d_in[11];
    const float* eW    = (const float*)d_in[12];
    const float* eb    = (const float*)d_in[13];
    const float* aW    = (const float*)d_in[14];
    const float* ab    = (const float*)d_in[15];

    float* p_out = (float*)d_out;
    float* Mv    = p_out + BB * NN;

    float* ws     = (float*)d_ws;
    float* w_ws   = ws;                                   // B*N*50      = 2.56M fl
    float* e_ws   = w_ws + (size_t)BB * NN * MSZ;         // B*N*128
    float* ad_ws  = e_ws + (size_t)BB * NN * DIM;         // B*N*128
    float* rp     = ad_ws + (size_t)BB * NN * DIM;        // B*N*128
    float* Aseg   = rp + (size_t)BB * NN * DIM;           // B*SEG*50*128
    float* Bseg   = Aseg + (size_t)BB * SEG * MSZ * DIM;  // B*SEG*50*128
    float* Mstart = Bseg + (size_t)BB * SEG * MSZ * DIM;  // B*SEG*50*128

    phaseA<<<BB * NN / RPOS, 128, 0, stream>>>(q, r, a, Kemb, Vemb, VAemb,
                                               Mk, eW, eb, aW, ab,
                                               w_ws, e_ws, ad_ws);
    scanP1<<<BB * 2 * SEG, 64, 0, stream>>>(w_ws, e_ws, ad_ws, Aseg, Bseg);
    scanC<<<BB * MSZ * DIM / 256, 256, 0, stream>>>(Mv0, Aseg, Bseg, Mstart, Mv);
    scanP2<<<BB * 2 * SEG, 64, 0, stream>>>(Mstart, w_ws, e_ws, ad_ws, rp, Mv);
    phaseC<<<BB * NN / RPOS, 128, 0, stream>>>(q, Kemb, rp, fW, fb, pW, pb, p_out);
}